// Round 2
// baseline (2771.826 us; speedup 1.0000x reference)
//
#include <hip/hip_runtime.h>
#include <hip/hip_bf16.h>

#define T_   20
#define B_   4
#define NN_  500
#define M_   2000
#define TM_  40000   // T_*M_
#define H_   128
#define G_   512     // 4*H_
#define H2_  64
#define OUT_ 32
#define ECAP 64

typedef unsigned short ushort_t;
typedef unsigned int   uint_t;
typedef _Float16       f16;
typedef f16 f16x2 __attribute__((ext_vector_type(2)));

#if defined(__has_builtin)
#  if __has_builtin(__builtin_amdgcn_fdot2)
#    define HAVE_FDOT2 1
#  endif
#endif

__device__ inline float fdot2_(f16x2 a, f16x2 b, float c) {
#ifdef HAVE_FDOT2
    return __builtin_amdgcn_fdot2(a, b, c, false);
#else
    return c + (float)a.x * (float)b.x + (float)a.y * (float)b.y;
#endif
}

__device__ inline float fast_sig(float x) {
    float e = __builtin_amdgcn_exp2f(x * -1.4426950408889634f);
    return __builtin_amdgcn_rcpf(1.f + e);   // x->-inf: e=inf, rcp=0 OK
}
__device__ inline float fast_tanh(float x) {
    float e = __builtin_amdgcn_exp2f(x * 2.8853900817779268f);
    return 1.f - 2.f * __builtin_amdgcn_rcpf(e + 1.f);  // saturates to +-1
}

// ---- K0: detect ego dtype (int32/uint8/f32/bf16) + build mask[t][i] ----
// single block, 1024 threads: detection scans first 10000 dwords (40000 B,
// the minimum possible buffer size), then decodes all 40000 elements.
__global__ __launch_bounds__(1024) void k0_mask(const void* __restrict__ ego,
                                                float* __restrict__ mf) {
    __shared__ int fl[3];   // 0: f32 pattern, 1: bf16 pattern, 2: >1 non-float
    int tid = threadIdx.x;
    if (tid < 3) fl[tid] = 0;
    __syncthreads();
    const uint_t* dw = (const uint_t*)ego;
    int a = 0, b = 0, c = 0;
    for (int i = tid; i < 10000; i += 1024) {
        uint_t v = dw[i];
        bool isf32  = (v == 0x3F800000u);
        bool isbf16 = (v == 0x00003F80u) || (v == 0x3F803F80u);
        if (isf32)  a = 1;
        if (isbf16) b = 1;
        if (v > 1u && !isf32 && !isbf16) c = 1;
    }
    if (a) fl[0] = 1;
    if (b) fl[1] = 1;
    if (c) fl[2] = 1;
    __syncthreads();
    int mode;                       // 0=int32, 1=uint8, 2=f32, 3=bf16
    if (fl[1])      mode = 3;
    else if (fl[0]) mode = 2;
    else if (fl[2]) mode = 1;
    else            mode = 0;
    for (int e = tid; e < TM_; e += 1024) {
        int t = e / M_, i = e % M_;
        int bb = i / NN_, n = i % NN_;
        int src = (bb * T_ + t) * NN_ + n;
        bool on;
        if (mode == 0)      on = ((const int*)ego)[src] != 0;
        else if (mode == 1) on = ((const unsigned char*)ego)[src] != 0;
        else if (mode == 2) on = ((const float*)ego)[src] != 0.f;
        else                on = ((const ushort_t*)ego)[src] != 0;
        mf[e] = on ? 1.f : 0.f;
    }
}

// ---- K1: single scan of adjacency (f32) -> edges, ecnt, dinv ----------
__global__ void k1_scan(const float* __restrict__ adj, const float* __restrict__ mf,
                        float* __restrict__ dinv, int* __restrict__ ecnt,
                        int* __restrict__ edges) {
    __shared__ float mrow[M_];
    int t = blockIdx.y;
    int i = blockIdx.x * 256 + threadIdx.x;
    for (int idx = threadIdx.x; idx < M_; idx += 256) mrow[idx] = mf[t * M_ + idx];
    __syncthreads();
    if (i >= M_) return;
    bool keep = (mrow[i] != 0.f);
    if (!keep) { ecnt[t * M_ + i] = 0; dinv[t * M_ + i] = 0.f; return; }
    const float* ap = adj + (size_t)t * M_ * M_ + i;   // column i, row stride M_
    int* ep = edges + (size_t)(t * M_ + i) * ECAP;
    int cnt = 0;
#pragma unroll 8
    for (int j = 0; j < M_; ++j) {
        float av = ap[(size_t)j * M_];
        if (av != 0.f && mrow[j] != 0.f) {
            if (cnt < ECAP) ep[cnt] = j;
            cnt++;
        }
    }
    ecnt[t * M_ + i] = (cnt < ECAP) ? cnt : ECAP;
    dinv[t * M_ + i] = __frsqrt_rn((float)(cnt + 1));   // deg = cnt + self loop
}

// ---- K2: Y1 = dinv * (x @ W1)  (dinv is mask-folded) ------------------
__global__ void k2_y1(const float* __restrict__ pos, const float* __restrict__ W1,
                      const float* __restrict__ dinv, f16* __restrict__ Y1) {
    int gid = blockIdx.x * 256 + threadIdx.x;    // over TM_*H_
    int r = gid / H_, h = gid % H_;
    if (r >= TM_) return;
    float2 xy = ((const float2*)pos)[r];
    float v = xy.x * W1[h] + xy.y * W1[H_ + h];
    Y1[gid] = (f16)(dinv[r] * v);
}

// ---- K3: h1 = relu(dinv*(sum_edges Y1 + Y1_self) + b1) ----------------
__global__ void k3_agg1(const f16* __restrict__ Y1, const float* __restrict__ dinv,
                        const int* __restrict__ ecnt, const int* __restrict__ edges,
                        const float* __restrict__ b1, f16* __restrict__ h1) {
    int r = blockIdx.x;          // t*M_ + i
    int h = threadIdx.x;
    int t = r / M_;
    float acc = (float)Y1[(size_t)r * H_ + h];   // self-loop term
    int ec = ecnt[r];
    const int* ep = edges + (size_t)r * ECAP;
    for (int e = 0; e < ec; ++e) {
        int j = ep[e];
        acc += (float)Y1[((size_t)(t * M_ + j)) * H_ + h];
    }
    float o = dinv[r] * acc + b1[h];
    h1[(size_t)r * H_ + h] = (f16)fmaxf(o, 0.f);
}

// ---- K5: placeholder = (dinv*(sum Y2 + Y2_self) + b2) * m -------------
__global__ void k5_agg2(const f16* __restrict__ Y2, const float* __restrict__ dinv,
                        const float* __restrict__ mf,
                        const int* __restrict__ ecnt, const int* __restrict__ edges,
                        const float* __restrict__ b2, f16* __restrict__ ph) {
    int r = blockIdx.x;
    int h = threadIdx.x;
    int t = r / M_;
    float acc = (float)Y2[(size_t)r * H_ + h];
    int ec = ecnt[r];
    const int* ep = edges + (size_t)r * ECAP;
    for (int e = 0; e < ec; ++e) {
        int j = ep[e];
        acc += (float)Y2[((size_t)(t * M_ + j)) * H_ + h];
    }
    float o = (dinv[r] * acc + b2[h]) * mf[r];
    ph[(size_t)r * H_ + h] = (f16)o;
}

// ---- GEMM: [TM_ x 128] f16 @ [128 x Ntot] f32 -> f16 ------------------
// bTrans=0: Bw stored [K=128][Ntot] (W2). bTrans=1: Bw stored [Ntot][128] (W_ih).
// mode=0: Out[r*Ntot+n] = dinv[r]*acc   (Y2)
// mode=1: Out[(s*T_+t)*G_+n] = acc + ba[n] + bb[n]   (xg, row r = t*M_+s)
#define BM 32
#define BN 64
#define BLD (BN + 4)   // 68 dwords: 16B-aligned rows
__global__ __launch_bounds__(256) void kgemm(const f16* __restrict__ A,
        const float* __restrict__ Bw, int bTrans, int Ntot, int mode,
        const float* __restrict__ dinv, const float* __restrict__ ba,
        const float* __restrict__ bb, f16* __restrict__ Out) {
    __shared__ float As[H_ * BM];      // [k][r], ld=32
    __shared__ float Bs[H_ * BLD];     // [k][n], ld=68
    int m0 = blockIdx.x * BM;
    int nb = blockIdx.y;
    int tid = threadIdx.x;
    {   // A tile: 32 rows x 128 k, transposed into LDS
        int r = tid >> 3, kc = tid & 7;
        const f16* aprow = A + (size_t)(m0 + r) * H_ + kc * 16;
        float4 raw0 = ((const float4*)aprow)[0];
        float4 raw1 = ((const float4*)aprow)[1];
        f16 tmp[16];
        *(float4*)(tmp) = raw0;
        *(float4*)(tmp + 8) = raw1;
#pragma unroll
        for (int u = 0; u < 16; ++u) As[(kc * 16 + u) * BM + r] = (float)tmp[u];
    }
    if (bTrans == 0) {
        for (int idx = tid; idx < H_ * BN; idx += 256) {
            int k = idx >> 6, nl = idx & 63;
            Bs[k * BLD + nl] = Bw[k * Ntot + nb * BN + nl];
        }
    } else {
        for (int idx = tid; idx < H_ * BN; idx += 256) {
            int nl = idx >> 7, k = idx & 127;
            Bs[k * BLD + nl] = Bw[(size_t)(nb * BN + nl) * H_ + k];
        }
    }
    __syncthreads();
    int ty = tid >> 4, tx = tid & 15;   // 16 x 16 threads -> 2 rows x 4 cols each
    float acc[2][4] = {};
#pragma unroll 4
    for (int k = 0; k < H_; ++k) {
        float2 a2 = *(const float2*)&As[k * BM + ty * 2];
        float4 b4 = *(const float4*)&Bs[k * BLD + tx * 4];
        acc[0][0] += a2.x * b4.x; acc[0][1] += a2.x * b4.y;
        acc[0][2] += a2.x * b4.z; acc[0][3] += a2.x * b4.w;
        acc[1][0] += a2.y * b4.x; acc[1][1] += a2.y * b4.y;
        acc[1][2] += a2.y * b4.z; acc[1][3] += a2.y * b4.w;
    }
#pragma unroll
    for (int rr = 0; rr < 2; ++rr) {
        int r = m0 + ty * 2 + rr;
        if (mode == 0) {
            float sc = dinv[r];
#pragma unroll
            for (int cc = 0; cc < 4; ++cc) {
                int n = nb * BN + tx * 4 + cc;
                Out[(size_t)r * Ntot + n] = (f16)(sc * acc[rr][cc]);
            }
        } else {
            int t = r / M_, s = r % M_;
#pragma unroll
            for (int cc = 0; cc < 4; ++cc) {
                int n = nb * BN + tx * 4 + cc;
                Out[((size_t)s * T_ + t) * G_ + n] =
                    (f16)(acc[rr][cc] + ba[n] + bb[n]);
            }
        }
    }
}

// ---- K7: 20 independent LSTM chains, 1 WG each ------------------------
// thread j owns gate j (0..511). W_hh row j in 64 packed-f16 VGPRs.
__global__ __launch_bounds__(512, 2) void k7_lstm(const float* __restrict__ Whh,
        const f16* __restrict__ xg, f16* __restrict__ lo) {
    __shared__ uint_t hbuf[H_ / 2];   // 128 f16
    __shared__ float g4[G_];          // sig(i), sig(f), tanh(g), sig(o)
    int t = blockIdx.x, j = threadIdx.x;
    f16x2 w[64];
    {
        const float* wr = Whh + (size_t)j * H_;
#pragma unroll
        for (int d = 0; d < 64; ++d) {
            f16x2 p;
            p.x = (f16)wr[2 * d];
            p.y = (f16)wr[2 * d + 1];
            w[d] = p;
        }
    }
    if (j < H_ / 2) hbuf[j] = 0;
    float c = 0.f;
    const f16* xp = xg + t * G_ + j;
    f16 xcur = xp[0];
    __syncthreads();
    for (int s = 0; s < M_; ++s) {
        f16 xnxt = (s + 1 < M_) ? xp[(size_t)(s + 1) * T_ * G_] : (f16)0.f;
        float acc = 0.f;
        const uint4* hb = (const uint4*)hbuf;
#pragma unroll
        for (int d = 0; d < 16; ++d) {
            uint4 hv = hb[d];   // broadcast ds_read_b128
            acc = fdot2_(w[4 * d + 0], __builtin_bit_cast(f16x2, hv.x), acc);
            acc = fdot2_(w[4 * d + 1], __builtin_bit_cast(f16x2, hv.y), acc);
            acc = fdot2_(w[4 * d + 2], __builtin_bit_cast(f16x2, hv.z), acc);
            acc = fdot2_(w[4 * d + 3], __builtin_bit_cast(f16x2, hv.w), acc);
        }
        acc += (float)xcur;
        int q = j >> 7;
        g4[j] = (q == 2) ? fast_tanh(acc) : fast_sig(acc);
        __syncthreads();   // gates ready; all dot-reads of hbuf done
        if (j < H_) {
            float si = g4[j], sf = g4[H_ + j], tg = g4[2 * H_ + j], so = g4[3 * H_ + j];
            c = sf * c + si * tg;
            float h = so * fast_tanh(c);
            f16 hh = (f16)h;
            ((ushort_t*)hbuf)[j] = __builtin_bit_cast(ushort_t, hh);
            lo[((size_t)s * T_ + t) * H_ + j] = hh;
        }
        xcur = xnxt;
        __syncthreads();   // new h visible
    }
}

// ---- K8: fused fc1(relu) + fc2 -> f32 out -----------------------------
__global__ __launch_bounds__(256) void k8_fc(const f16* __restrict__ lo,
        const float* __restrict__ w1, const float* __restrict__ fb1,
        const float* __restrict__ w2, const float* __restrict__ fb2,
        float* __restrict__ out) {
    __shared__ float W1s[H_ * H2_];
    __shared__ float W2s[H2_ * OUT_];
    __shared__ float hrow[4][H_];
    __shared__ float o1[4][H2_];
    int tid = threadIdx.x;
    for (int idx = tid; idx < H_ * H2_; idx += 256) W1s[idx] = w1[idx];
    for (int idx = tid; idx < H2_ * OUT_; idx += 256) W2s[idx] = w2[idx];
    int row0 = blockIdx.x * 4;
    for (int idx = tid; idx < 4 * H_; idx += 256) {
        int rr = idx >> 7, k = idx & 127;
        hrow[rr][k] = (float)lo[(size_t)(row0 + rr) * H_ + k];
    }
    __syncthreads();
    int rr = tid >> 6, o = tid & 63;
    float acc = fb1[o];
#pragma unroll 4
    for (int k = 0; k < H_; ++k) acc += hrow[rr][k] * W1s[k * H2_ + o];
    o1[rr][o] = fmaxf(acc, 0.f);
    __syncthreads();
    if (o < OUT_) {
        float a2 = fb2[o];
#pragma unroll 4
        for (int k = 0; k < H2_; ++k) a2 += o1[rr][k] * W2s[k * OUT_ + o];
        out[(size_t)(row0 + rr) * OUT_ + o] = a2;
    }
}

// ---- K9: health sideband. out[0] += 1000*code; code==0 when healthy ---
__global__ void k9_health(const float* __restrict__ mf, const float* __restrict__ dinv,
                          const f16* __restrict__ ph, const f16* __restrict__ xg,
                          const f16* __restrict__ lo, float* __restrict__ out) {
    __shared__ int nz[5];
    int tid = threadIdx.x;
    if (tid < 5) nz[tid] = 0;
    __syncthreads();
    int a = 0, b = 0, c = 0, d = 0, e = 0;
    for (int k = tid; k < 1024; k += 256) {
        a |= (mf[k * 39] != 0.f);
        b |= (dinv[k * 39] != 0.f);
        c |= ((float)ph[(size_t)k * 4999] != 0.f);
        d |= ((float)xg[(size_t)k * 19999] != 0.f);
        e |= ((float)lo[(size_t)k * 4999] != 0.f);
    }
    if (a) nz[0] = 1;
    if (b) nz[1] = 1;
    if (c) nz[2] = 1;
    if (d) nz[3] = 1;
    if (e) nz[4] = 1;
    __syncthreads();
    if (tid == 0) {
        int code = (!nz[0]) | ((!nz[1]) << 1) | ((!nz[2]) << 2)
                 | ((!nz[3]) << 3) | ((!nz[4]) << 4);
        out[0] += 1000.f * (float)code;   // adds 0.0 when healthy
    }
}

extern "C" void kernel_launch(void* const* d_in, const int* in_sizes, int n_in,
                              void* d_out, int out_size, void* d_ws, size_t ws_size,
                              hipStream_t stream) {
    const float* positions = (const float*)d_in[0];   // f32 [T,M,2]
    const float* adjacency = (const float*)d_in[1];   // f32 [T,M,M]
    const void*  ego       = d_in[2];                 // bool, dtype auto-detected
    const float* W1   = (const float*)d_in[3];
    const float* b1   = (const float*)d_in[4];
    const float* W2   = (const float*)d_in[5];
    const float* b2   = (const float*)d_in[6];
    const float* W_ih = (const float*)d_in[7];
    const float* W_hh = (const float*)d_in[8];
    const float* b_ih = (const float*)d_in[9];
    const float* b_hh = (const float*)d_in[10];
    const float* fc1w = (const float*)d_in[11];
    const float* fc1b = (const float*)d_in[12];
    const float* fc2w = (const float*)d_in[13];
    const float* fc2b = (const float*)d_in[14];
    float* out = (float*)d_out;

    char* p = (char*)d_ws;
    auto alloc = [&](size_t bytes) {
        void* r = (void*)p;
        p += (bytes + 255) & ~(size_t)255;
        return r;
    };
    float* mf    = (float*)alloc((size_t)TM_ * 4);
    float* dinv  = (float*)alloc((size_t)TM_ * 4);
    int*   ecnt  = (int*)alloc((size_t)TM_ * 4);
    int*   edges = (int*)alloc((size_t)TM_ * ECAP * 4);   // later aliased by lo
    f16*   bufC  = (f16*)alloc((size_t)TM_ * H_ * 2);     // Y1, then Y2
    f16*   bufD  = (f16*)alloc((size_t)TM_ * H_ * 2);     // h1, then ph
    f16*   xg    = (f16*)alloc((size_t)TM_ * G_ * 2);
    f16*   Y1 = bufC, *Y2 = bufC;
    f16*   h1 = bufD, *ph = bufD;
    f16*   lo = (f16*)edges;    // edges dead after k5
    // total ~72 MB of d_ws

    hipLaunchKernelGGL(k0_mask, dim3(1), dim3(1024), 0, stream, ego, mf);
    hipLaunchKernelGGL(k1_scan, dim3(8, 20), dim3(256), 0, stream,
                       adjacency, mf, dinv, ecnt, edges);
    hipLaunchKernelGGL(k2_y1, dim3(20000), dim3(256), 0, stream,
                       positions, W1, dinv, Y1);
    hipLaunchKernelGGL(k3_agg1, dim3(40000), dim3(128), 0, stream,
                       Y1, dinv, ecnt, edges, b1, h1);
    hipLaunchKernelGGL(kgemm, dim3(1250, 2), dim3(256), 0, stream,
                       h1, W2, 0, 128, 0, dinv, (const float*)nullptr,
                       (const float*)nullptr, Y2);
    hipLaunchKernelGGL(k5_agg2, dim3(40000), dim3(128), 0, stream,
                       Y2, dinv, mf, ecnt, edges, b2, ph);
    hipLaunchKernelGGL(kgemm, dim3(1250, 8), dim3(256), 0, stream,
                       ph, W_ih, 1, 512, 1, dinv, b_ih, b_hh, xg);
    hipLaunchKernelGGL(k7_lstm, dim3(20), dim3(512), 0, stream, W_hh, xg, lo);
    hipLaunchKernelGGL(k8_fc, dim3(10000), dim3(256), 0, stream,
                       lo, fc1w, fc1b, fc2w, fc2b, out);
    hipLaunchKernelGGL(k9_health, dim3(1), dim3(256), 0, stream,
                       mf, dinv, ph, xg, lo, out);
}

// Round 3
// 1913.873 us; speedup vs baseline: 1.4483x; 1.4483x over previous
//
#include <hip/hip_runtime.h>
#include <hip/hip_bf16.h>

#define T_   20
#define B_   4
#define NN_  500
#define M_   2000
#define TM_  40000   // T_*M_
#define H_   128
#define G_   512     // 4*H_
#define H2_  64
#define OUT_ 32
#define ECAP 64
#define TG_  (T_ * G_)

typedef unsigned short ushort_t;
typedef unsigned int   uint_t;
typedef _Float16       f16;
typedef f16 f16x2 __attribute__((ext_vector_type(2)));

#if defined(__has_builtin)
#  if __has_builtin(__builtin_amdgcn_fdot2)
#    define HAVE_FDOT2 1
#  endif
#endif

__device__ inline float fdot2_(f16x2 a, f16x2 b, float c) {
#ifdef HAVE_FDOT2
    return __builtin_amdgcn_fdot2(a, b, c, false);
#else
    return c + (float)a.x * (float)b.x + (float)a.y * (float)b.y;
#endif
}

__device__ inline float fast_sig(float x) {
    float e = __builtin_amdgcn_exp2f(x * -1.4426950408889634f);
    return __builtin_amdgcn_rcpf(1.f + e);
}
__device__ inline float fast_tanh(float x) {
    float e = __builtin_amdgcn_exp2f(x * 2.8853900817779268f);
    return 1.f - 2.f * __builtin_amdgcn_rcpf(e + 1.f);
}

// raw barrier: no compiler-inserted s_waitcnt vmcnt(0) drain (k7 only).
// Safe because the LDS pipe is in-order per CU: ds ops issued before the
// barrier land before ds ops issued after it.
#define BARRAW() asm volatile("s_barrier" ::: "memory")

// ---- K0: detect ego dtype + build mask[t][i] + zero ecnt ---------------
__global__ __launch_bounds__(1024) void k0_mask(const void* __restrict__ ego,
                                                float* __restrict__ mf,
                                                int* __restrict__ ecnt) {
    __shared__ int fl[3];
    int tid = threadIdx.x;
    if (tid < 3) fl[tid] = 0;
    __syncthreads();
    const uint_t* dw = (const uint_t*)ego;
    int a = 0, b = 0, c = 0;
    for (int i = tid; i < 2500; i += 1024) {   // 10 KB <= any dtype's size
        uint_t v = dw[i];
        bool isf32  = (v == 0x3F800000u);
        bool isbf16 = (v == 0x00003F80u) || (v == 0x3F803F80u);
        if (isf32)  a = 1;
        if (isbf16) b = 1;
        if (v > 1u && !isf32 && !isbf16) c = 1;
    }
    if (a) fl[0] = 1;
    if (b) fl[1] = 1;
    if (c) fl[2] = 1;
    __syncthreads();
    int mode;                       // 0=int32, 1=uint8, 2=f32, 3=bf16
    if (fl[1])      mode = 3;
    else if (fl[0]) mode = 2;
    else if (fl[2]) mode = 1;
    else            mode = 0;
    int e = blockIdx.x * 1024 + tid;
    if (e >= TM_) return;
    ecnt[e] = 0;
    int t = e / M_, i = e % M_;
    int bb = i / NN_, n = i % NN_;
    int src = (bb * T_ + t) * NN_ + n;
    bool on;
    if (mode == 0)      on = ((const int*)ego)[src] != 0;
    else if (mode == 1) on = ((const unsigned char*)ego)[src] != 0;
    else if (mode == 2) on = ((const float*)ego)[src] != 0.f;
    else                on = ((const ushort_t*)ego)[src] != 0;
    mf[e] = on ? 1.f : 0.f;
}

// ---- K1: strip-parallel adjacency scan, atomic slot alloc --------------
#define JSTRIP 400
__global__ void k1_scan(const float* __restrict__ adj, const float* __restrict__ mf,
                        int* __restrict__ ecnt, int* __restrict__ edges) {
    __shared__ float ms[JSTRIP];
    int t = blockIdx.y, j0 = blockIdx.z * JSTRIP;
    int i = blockIdx.x * 256 + threadIdx.x;
    for (int idx = threadIdx.x; idx < JSTRIP; idx += 256)
        ms[idx] = mf[t * M_ + j0 + idx];
    __syncthreads();
    if (i >= M_) return;
    if (mf[t * M_ + i] == 0.f) return;          // masked column: no edges
    const float* ap = adj + (size_t)t * M_ * M_ + (size_t)j0 * M_ + i;
    int r = t * M_ + i;
    int* ep = edges + (size_t)r * ECAP;
#pragma unroll 8
    for (int jj = 0; jj < JSTRIP; ++jj) {
        float av = ap[(size_t)jj * M_];
        if (av != 0.f && ms[jj] != 0.f) {
            int pos = atomicAdd(&ecnt[r], 1);
            if (pos < ECAP) ep[pos] = j0 + jj;
        }
    }
}

// ---- K2: dinv from ecnt/mf; Y1 = dinv * (x @ W1) -----------------------
__global__ void k2_y1(const float* __restrict__ pos, const float* __restrict__ W1,
                      const float* __restrict__ mf, const int* __restrict__ ecnt,
                      float* __restrict__ dinv, f16* __restrict__ Y1) {
    int gid = blockIdx.x * 256 + threadIdx.x;    // over TM_*H_
    int r = gid >> 7, h = gid & 127;
    if (r >= TM_) return;
    float mr = mf[r];
    int cnt = ecnt[r];
    float dv = (mr != 0.f) ? __frsqrt_rn((float)(cnt + 1)) : 0.f;
    if (h == 0) dinv[r] = dv;
    float2 xy = ((const float2*)pos)[r];
    float v = xy.x * W1[h] + xy.y * W1[H_ + h];
    Y1[gid] = (f16)(dv * v);
}

// ---- K3: h1 = relu(dinv*(sum_edges Y1 + Y1_self) + b1), f16x2 lanes ----
__global__ __launch_bounds__(64) void k3_agg1(const f16* __restrict__ Y1,
        const float* __restrict__ dinv, const int* __restrict__ ecnt,
        const int* __restrict__ edges, const float* __restrict__ b1,
        f16* __restrict__ h1) {
    int r = blockIdx.x, q = threadIdx.x;   // q: h-pair index 0..63
    int t = r / M_, base = t * M_;
    const uint_t* Yu = (const uint_t*)Y1;
    f16x2 sp = __builtin_bit_cast(f16x2, Yu[(size_t)r * 64 + q]);
    float a0 = (float)sp.x, a1 = (float)sp.y;
    int ec = ecnt[r]; if (ec > ECAP) ec = ECAP;
    const int4* ep4 = (const int4*)(edges + (size_t)r * ECAP);
    for (int e = 0; e < ec; e += 4) {
        int4 ix = ep4[e >> 2];
        int j1 = (e + 1 < ec) ? ix.y : ix.x;
        int j2 = (e + 2 < ec) ? ix.z : ix.x;
        int j3 = (e + 3 < ec) ? ix.w : ix.x;
        uint_t u0 = Yu[(size_t)(base + ix.x) * 64 + q];
        uint_t u1 = Yu[(size_t)(base + j1) * 64 + q];
        uint_t u2 = Yu[(size_t)(base + j2) * 64 + q];
        uint_t u3 = Yu[(size_t)(base + j3) * 64 + q];
        f16x2 p0 = __builtin_bit_cast(f16x2, u0);
        a0 += (float)p0.x; a1 += (float)p0.y;
        if (e + 1 < ec) { f16x2 p = __builtin_bit_cast(f16x2, u1); a0 += (float)p.x; a1 += (float)p.y; }
        if (e + 2 < ec) { f16x2 p = __builtin_bit_cast(f16x2, u2); a0 += (float)p.x; a1 += (float)p.y; }
        if (e + 3 < ec) { f16x2 p = __builtin_bit_cast(f16x2, u3); a0 += (float)p.x; a1 += (float)p.y; }
    }
    float dv = dinv[r];
    float o0 = dv * a0 + b1[2 * q];
    float o1 = dv * a1 + b1[2 * q + 1];
    f16x2 op; op.x = (f16)fmaxf(o0, 0.f); op.y = (f16)fmaxf(o1, 0.f);
    ((uint_t*)h1)[(size_t)r * 64 + q] = __builtin_bit_cast(uint_t, op);
}

// ---- K5: placeholder = (dinv*(sum Y2 + Y2_self) + b2) * m --------------
__global__ __launch_bounds__(64) void k5_agg2(const f16* __restrict__ Y2,
        const float* __restrict__ dinv, const float* __restrict__ mf,
        const int* __restrict__ ecnt, const int* __restrict__ edges,
        const float* __restrict__ b2, f16* __restrict__ ph) {
    int r = blockIdx.x, q = threadIdx.x;
    int t = r / M_, base = t * M_;
    const uint_t* Yu = (const uint_t*)Y2;
    f16x2 sp = __builtin_bit_cast(f16x2, Yu[(size_t)r * 64 + q]);
    float a0 = (float)sp.x, a1 = (float)sp.y;
    int ec = ecnt[r]; if (ec > ECAP) ec = ECAP;
    const int4* ep4 = (const int4*)(edges + (size_t)r * ECAP);
    for (int e = 0; e < ec; e += 4) {
        int4 ix = ep4[e >> 2];
        int j1 = (e + 1 < ec) ? ix.y : ix.x;
        int j2 = (e + 2 < ec) ? ix.z : ix.x;
        int j3 = (e + 3 < ec) ? ix.w : ix.x;
        uint_t u0 = Yu[(size_t)(base + ix.x) * 64 + q];
        uint_t u1 = Yu[(size_t)(base + j1) * 64 + q];
        uint_t u2 = Yu[(size_t)(base + j2) * 64 + q];
        uint_t u3 = Yu[(size_t)(base + j3) * 64 + q];
        f16x2 p0 = __builtin_bit_cast(f16x2, u0);
        a0 += (float)p0.x; a1 += (float)p0.y;
        if (e + 1 < ec) { f16x2 p = __builtin_bit_cast(f16x2, u1); a0 += (float)p.x; a1 += (float)p.y; }
        if (e + 2 < ec) { f16x2 p = __builtin_bit_cast(f16x2, u2); a0 += (float)p.x; a1 += (float)p.y; }
        if (e + 3 < ec) { f16x2 p = __builtin_bit_cast(f16x2, u3); a0 += (float)p.x; a1 += (float)p.y; }
    }
    float dv = dinv[r], mr = mf[r];
    f16x2 op;
    op.x = (f16)((dv * a0 + b2[2 * q]) * mr);
    op.y = (f16)((dv * a1 + b2[2 * q + 1]) * mr);
    ((uint_t*)ph)[(size_t)r * 64 + q] = __builtin_bit_cast(uint_t, op);
}

// ---- GEMM: [TM_ x 128] f16 @ [128 x Ntot] f32 -> f16 (unchanged) -------
#define BM 32
#define BN 64
#define BLD (BN + 4)
__global__ __launch_bounds__(256) void kgemm(const f16* __restrict__ A,
        const float* __restrict__ Bw, int bTrans, int Ntot, int mode,
        const float* __restrict__ dinv, const float* __restrict__ ba,
        const float* __restrict__ bb, f16* __restrict__ Out) {
    __shared__ float As[H_ * BM];
    __shared__ float Bs[H_ * BLD];
    int m0 = blockIdx.x * BM;
    int nb = blockIdx.y;
    int tid = threadIdx.x;
    {
        int r = tid >> 3, kc = tid & 7;
        const f16* aprow = A + (size_t)(m0 + r) * H_ + kc * 16;
        float4 raw0 = ((const float4*)aprow)[0];
        float4 raw1 = ((const float4*)aprow)[1];
        f16 tmp[16];
        *(float4*)(tmp) = raw0;
        *(float4*)(tmp + 8) = raw1;
#pragma unroll
        for (int u = 0; u < 16; ++u) As[(kc * 16 + u) * BM + r] = (float)tmp[u];
    }
    if (bTrans == 0) {
        for (int idx = tid; idx < H_ * BN; idx += 256) {
            int k = idx >> 6, nl = idx & 63;
            Bs[k * BLD + nl] = Bw[k * Ntot + nb * BN + nl];
        }
    } else {
        for (int idx = tid; idx < H_ * BN; idx += 256) {
            int nl = idx >> 7, k = idx & 127;
            Bs[k * BLD + nl] = Bw[(size_t)(nb * BN + nl) * H_ + k];
        }
    }
    __syncthreads();
    int ty = tid >> 4, tx = tid & 15;
    float acc[2][4] = {};
#pragma unroll 4
    for (int k = 0; k < H_; ++k) {
        float2 a2 = *(const float2*)&As[k * BM + ty * 2];
        float4 b4 = *(const float4*)&Bs[k * BLD + tx * 4];
        acc[0][0] += a2.x * b4.x; acc[0][1] += a2.x * b4.y;
        acc[0][2] += a2.x * b4.z; acc[0][3] += a2.x * b4.w;
        acc[1][0] += a2.y * b4.x; acc[1][1] += a2.y * b4.y;
        acc[1][2] += a2.y * b4.z; acc[1][3] += a2.y * b4.w;
    }
#pragma unroll
    for (int rr = 0; rr < 2; ++rr) {
        int r = m0 + ty * 2 + rr;
        if (mode == 0) {
            float sc = dinv[r];
#pragma unroll
            for (int cc = 0; cc < 4; ++cc) {
                int n = nb * BN + tx * 4 + cc;
                Out[(size_t)r * Ntot + n] = (f16)(sc * acc[rr][cc]);
            }
        } else {
            int t = r / M_, s = r % M_;
#pragma unroll
            for (int cc = 0; cc < 4; ++cc) {
                int n = nb * BN + tx * 4 + cc;
                Out[((size_t)s * T_ + t) * G_ + n] =
                    (f16)(acc[rr][cc] + ba[n] + bb[n]);
            }
        }
    }
}

// ---- K7: 20 LSTM chains; reg-double-buffered x prefetch; raw barriers --
__global__ __launch_bounds__(512, 2) void k7_lstm(const float* __restrict__ Whh,
        const f16* __restrict__ xg, f16* __restrict__ lo) {
    __shared__ uint_t hbuf[H_ / 2];   // 128 f16
    __shared__ float g4[G_];
    int t = blockIdx.x, j = threadIdx.x;
    f16x2 w[64];
    {
        const float* wr = Whh + (size_t)j * H_;
#pragma unroll
        for (int d = 0; d < 64; ++d) {
            f16x2 p;
            p.x = (f16)wr[2 * d];
            p.y = (f16)wr[2 * d + 1];
            w[d] = p;
        }
    }
    if (j < H_ / 2) hbuf[j] = 0;
    float cst = 0.f;
    const ushort_t* xpu = (const ushort_t*)xg + t * G_ + j;
    ushort_t xa[8], xb[8];
#pragma unroll
    for (int k = 0; k < 8; ++k) xa[k] = xpu[(size_t)k * TG_];
    __syncthreads();   // full barrier once: hbuf init + prologue loads

#define LSTM_STEP(S, XV)                                                      \
    do {                                                                      \
        float acc = 0.f;                                                      \
        const uint4* hb = (const uint4*)hbuf;                                 \
        _Pragma("unroll")                                                     \
        for (int d = 0; d < 16; ++d) {                                        \
            uint4 hv = hb[d];                                                 \
            acc = fdot2_(w[4 * d + 0], __builtin_bit_cast(f16x2, hv.x), acc); \
            acc = fdot2_(w[4 * d + 1], __builtin_bit_cast(f16x2, hv.y), acc); \
            acc = fdot2_(w[4 * d + 2], __builtin_bit_cast(f16x2, hv.z), acc); \
            acc = fdot2_(w[4 * d + 3], __builtin_bit_cast(f16x2, hv.w), acc); \
        }                                                                     \
        acc += (float)__builtin_bit_cast(f16, (ushort_t)(XV));                \
        g4[j] = ((j >> 7) == 2) ? fast_tanh(acc) : fast_sig(acc);             \
        BARRAW();                                                             \
        if (j < H_) {                                                         \
            float si = g4[j], sf = g4[H_ + j];                                \
            float tg = g4[2 * H_ + j], so = g4[3 * H_ + j];                   \
            cst = sf * cst + si * tg;                                         \
            float h = so * fast_tanh(cst);                                    \
            f16 hh = (f16)h;                                                  \
            ((ushort_t*)hbuf)[j] = __builtin_bit_cast(ushort_t, hh);          \
            lo[((size_t)(S) * T_ + t) * H_ + j] = hh;                         \
        }                                                                     \
        BARRAW();                                                             \
    } while (0)

    for (int c2 = 0; c2 < 125; ++c2) {
        int sA = c2 * 16;
        // prefetch steps sA+8..sA+15 into xb (consumed ~8 steps later)
#pragma unroll
        for (int k = 0; k < 8; ++k) xb[k] = xpu[(size_t)(sA + 8 + k) * TG_];
#pragma unroll
        for (int k = 0; k < 8; ++k) LSTM_STEP(sA + k, xa[k]);
        // prefetch steps sA+16..+23 into xa (clamped at the tail)
        int nbs = (sA + 16 <= TM_ / T_ - 8) ? sA + 16 : TM_ / T_ - 8;
#pragma unroll
        for (int k = 0; k < 8; ++k) xa[k] = xpu[(size_t)(nbs + k) * TG_];
#pragma unroll
        for (int k = 0; k < 8; ++k) LSTM_STEP(sA + 8 + k, xb[k]);
    }
#undef LSTM_STEP
}

// ---- K8: fc1(relu)+fc2; weights in VGPRs; stream 4 rows/iter -----------
__global__ __launch_bounds__(256) void k8_fc(const f16* __restrict__ lo,
        const float* __restrict__ w1, const float* __restrict__ fb1,
        const float* __restrict__ w2, const float* __restrict__ fb2,
        float* __restrict__ out) {
    __shared__ uint_t hl[4][H_ / 2];   // 4 rows x 128 f16
    __shared__ float o1f[4][H2_];
    int tid = threadIdx.x;
    int o = tid & 63, rr = tid >> 6;
    f16x2 w1c[64];
#pragma unroll
    for (int d = 0; d < 64; ++d) {
        f16x2 p;
        p.x = (f16)w1[(2 * d) * H2_ + o];
        p.y = (f16)w1[(2 * d + 1) * H2_ + o];
        w1c[d] = p;
    }
    int o2 = o & 31;
    float w2f[64];
#pragma unroll
    for (int d = 0; d < 64; ++d) w2f[d] = w2[d * OUT_ + o2];
    float fb1v = fb1[o], fb2v = fb2[o2];

    for (int r0 = blockIdx.x * 4; r0 < TM_; r0 += 512 * 4) {
        // stage 4 rows of lo
        {
            int row = tid >> 6, q = tid & 63;
            hl[row][q] = ((const uint_t*)lo)[(size_t)(r0 + row) * 64 + q];
        }
        __syncthreads();
        float acc = fb1v;
        const uint4* hb = (const uint4*)&hl[rr][0];
#pragma unroll
        for (int d = 0; d < 16; ++d) {
            uint4 hv = hb[d];
            acc = fdot2_(w1c[4 * d + 0], __builtin_bit_cast(f16x2, hv.x), acc);
            acc = fdot2_(w1c[4 * d + 1], __builtin_bit_cast(f16x2, hv.y), acc);
            acc = fdot2_(w1c[4 * d + 2], __builtin_bit_cast(f16x2, hv.z), acc);
            acc = fdot2_(w1c[4 * d + 3], __builtin_bit_cast(f16x2, hv.w), acc);
        }
        o1f[rr][o] = fmaxf(acc, 0.f);
        __syncthreads();
        if (o < OUT_) {
            float a2 = fb2v;
            const float4* ob = (const float4*)&o1f[rr][0];
#pragma unroll
            for (int d = 0; d < 16; ++d) {
                float4 v = ob[d];
                a2 += v.x * w2f[4 * d + 0] + v.y * w2f[4 * d + 1]
                    + v.z * w2f[4 * d + 2] + v.w * w2f[4 * d + 3];
            }
            out[(size_t)(r0 + rr) * OUT_ + o] = a2;
        }
        __syncthreads();   // o1f/hl reuse hazard
    }
}

extern "C" void kernel_launch(void* const* d_in, const int* in_sizes, int n_in,
                              void* d_out, int out_size, void* d_ws, size_t ws_size,
                              hipStream_t stream) {
    const float* positions = (const float*)d_in[0];
    const float* adjacency = (const float*)d_in[1];
    const void*  ego       = d_in[2];
    const float* W1   = (const float*)d_in[3];
    const float* b1   = (const float*)d_in[4];
    const float* W2   = (const float*)d_in[5];
    const float* b2   = (const float*)d_in[6];
    const float* W_ih = (const float*)d_in[7];
    const float* W_hh = (const float*)d_in[8];
    const float* b_ih = (const float*)d_in[9];
    const float* b_hh = (const float*)d_in[10];
    const float* fc1w = (const float*)d_in[11];
    const float* fc1b = (const float*)d_in[12];
    const float* fc2w = (const float*)d_in[13];
    const float* fc2b = (const float*)d_in[14];
    float* out = (float*)d_out;

    char* p = (char*)d_ws;
    auto alloc = [&](size_t bytes) {
        void* r = (void*)p;
        p += (bytes + 255) & ~(size_t)255;
        return r;
    };
    float* mf    = (float*)alloc((size_t)TM_ * 4);
    float* dinv  = (float*)alloc((size_t)TM_ * 4);
    int*   ecnt  = (int*)alloc((size_t)TM_ * 4);
    int*   edges = (int*)alloc((size_t)TM_ * ECAP * 4);   // aliased by lo later
    f16*   bufC  = (f16*)alloc((size_t)TM_ * H_ * 2);     // Y1, then Y2
    f16*   bufD  = (f16*)alloc((size_t)TM_ * H_ * 2);     // h1, then ph
    f16*   xg    = (f16*)alloc((size_t)TM_ * G_ * 2);
    f16*   Y1 = bufC, *Y2 = bufC;
    f16*   h1 = bufD, *ph = bufD;
    f16*   lo = (f16*)edges;    // edges dead after k5

    hipLaunchKernelGGL(k0_mask, dim3(40), dim3(1024), 0, stream, ego, mf, ecnt);
    hipLaunchKernelGGL(k1_scan, dim3(8, 20, 5), dim3(256), 0, stream,
                       adjacency, mf, ecnt, edges);
    hipLaunchKernelGGL(k2_y1, dim3(20000), dim3(256), 0, stream,
                       positions, W1, mf, ecnt, dinv, Y1);
    hipLaunchKernelGGL(k3_agg1, dim3(40000), dim3(64), 0, stream,
                       Y1, dinv, ecnt, edges, b1, h1);
    hipLaunchKernelGGL(kgemm, dim3(1250, 2), dim3(256), 0, stream,
                       h1, W2, 0, 128, 0, dinv, (const float*)nullptr,
                       (const float*)nullptr, Y2);
    hipLaunchKernelGGL(k5_agg2, dim3(40000), dim3(64), 0, stream,
                       Y2, dinv, mf, ecnt, edges, b2, ph);
    hipLaunchKernelGGL(kgemm, dim3(1250, 8), dim3(256), 0, stream,
                       ph, W_ih, 1, 512, 1, dinv, b_ih, b_hh, xg);
    hipLaunchKernelGGL(k7_lstm, dim3(20), dim3(512), 0, stream, W_hh, xg, lo);
    hipLaunchKernelGGL(k8_fc, dim3(512), dim3(256), 0, stream,
                       lo, fc1w, fc1b, fc2w, fc2b, out);
}